// Round 11
// baseline (140.751 us; speedup 1.0000x reference)
//
#include <hip/hip_runtime.h>
#include <stdint.h>

#define A_DIM 8192
#define B_DIM 8192
#define K_CL  256
#define NSLAB 8
#define SLABW (B_DIM / NSLAB)   // 1024
#define NKS   (SLABW / 64)      // 16 K-steps of 64

typedef short bf16x8 __attribute__((ext_vector_type(8)));
typedef float f32x4  __attribute__((ext_vector_type(4)));
typedef float f32x16 __attribute__((ext_vector_type(16)));
typedef unsigned short u16;

__device__ __forceinline__ u16 f2bf(float f) {
    unsigned int u = __float_as_uint(f);
    u += 0x7fffu + ((u >> 16) & 1u);   // RNE (prep only)
    return (u16)(u >> 16);
}

// ---------- prep: pack p_r into 32x32x16 MFMA B-fragment layout, bf16 ----------
// Bpack[((kb2*8 + c2)*64 + lane)*8 + j] = bf16(p_r[kb2*16 + (lane>>5)*8 + j][c2*32 + (lane&31)])
__global__ __launch_bounds__(256) void k_prep(const float* __restrict__ pr,
                                              u16* __restrict__ Bpack,
                                              float* __restrict__ out) {
    const int kb2 = blockIdx.x;          // 0..511
    const int t = threadIdx.x;
    if (kb2 == 0 && t == 0) out[0] = 0.0f;
    const int lane = t & 63, wv = t >> 6;
    const int l31 = lane & 31, half = lane >> 5;
#pragma unroll
    for (int ci = 0; ci < 2; ci++) {
        const int c2 = wv * 2 + ci;
        float v[8];
#pragma unroll
        for (int j = 0; j < 8; j++)
            v[j] = pr[(size_t)(kb2 * 16 + half * 8 + j) * K_CL + c2 * 32 + l31];
        union { bf16x8 b; unsigned int u[4]; } o;
#pragma unroll
        for (int j = 0; j < 4; j++)
            o.u[j] = (unsigned int)f2bf(v[2 * j]) | ((unsigned int)f2bf(v[2 * j + 1]) << 16);
        *(bf16x8*)(Bpack + ((size_t)(kb2 * 8 + c2) * 64 + lane) * 8) = o.b;
    }
}

// ---------- main: 8-wave blocks, 16 waves/CU, lean-VGPR pipeline ----------
__global__ __launch_bounds__(512, 4) void k_main(const float* __restrict__ w,
                                                 const float* __restrict__ pl,
                                                 const u16* __restrict__ Bpack,
                                                 const float* __restrict__ cp,
                                                 float* __restrict__ out) {
    __shared__ u16 Abuf[2][64 * 64];     // 2 x 8 KB bf16, row = 128 B, XOR-swizzled
    __shared__ float rowsum_s[64];
    __shared__ float red[8];

    const int bid = blockIdx.x;
    const int slab = bid & 7;            // XCD-pinned: Bpack slice (512 KB) stays L2-hot
    const int m0 = (bid >> 3) * 64;
    const int tid = threadIdx.x;
    const int lane = tid & 63, wv = tid >> 6;
    const int l31 = lane & 31, half = lane >> 5;
    const int kb2base = slab * 64;

    // staging: thread owns rows srow and 32+srow, f32 cols (tid&15)*4..+3 of each 64x64 tile
    const int srow = tid >> 4;           // 0..31
    const int scol8 = (tid & 15) * 8;    // byte offset in bf16 row
    const float* wthr = w + (size_t)(m0 + srow) * B_DIM + (size_t)slab * SLABW + (tid & 15) * 4;

    const int wb0 = srow * 128 + (scol8 ^ ((srow & 7) << 4));
    const int wb1 = wb0 + 32 * 128;      // (32+srow)&7 == srow&7

    float sm0 = 0.f, sm1 = 0.f;          // exact f32 row-sum partials
    f32x16 acc0, acc1;                   // rows 0-31 / 32-63  x  cols wv*32+l31
#pragma unroll
    for (int r = 0; r < 16; r++) { acc0[r] = 0.f; acc1[r] = 0.f; }

    f32x4 GA0, GA1, GB0, GB1;
    bf16x8 BX[4], BY[4];

#define SB0 __builtin_amdgcn_sched_barrier(0)
#define WAITV(n) do { asm volatile("s_waitcnt vmcnt(" #n ")" ::: "memory"); SB0; } while (0)
#define LGKM0BAR do { asm volatile("s_waitcnt lgkmcnt(0)" ::: "memory"); \
                      __builtin_amdgcn_s_barrier(); SB0; } while (0)

#define GLOAD(G0_, G1_, ks) do {                                                         \
        G0_ = *(const f32x4*)(wthr + (size_t)(ks) * 64);                                 \
        G1_ = *(const f32x4*)(wthr + 32 * B_DIM + (size_t)(ks) * 64);                    \
        SB0;                                                                             \
    } while (0)

#define LOADB(BS, s_) do {                                                               \
        _Pragma("unroll")                                                                \
        for (int kf_ = 0; kf_ < 4; kf_++)                                                \
            BS[kf_] = *(const bf16x8*)(Bpack +                                           \
                ((size_t)((kb2base + (s_) * 4 + kf_) * 8 + wv)) * 512 + lane * 8);       \
        SB0;                                                                             \
    } while (0)

#define PERM2(hi, lo) __builtin_amdgcn_perm(__float_as_uint(hi), __float_as_uint(lo), 0x07060302u)

#define CONV(G0_, G1_, bufi) do {                                                        \
        sm0 += G0_[0] + G0_[1] + G0_[2] + G0_[3];                                        \
        sm1 += G1_[0] + G1_[1] + G1_[2] + G1_[3];                                        \
        uint2 p0_, p1_;                                                                  \
        p0_.x = PERM2(G0_[1], G0_[0]); p0_.y = PERM2(G0_[3], G0_[2]);                    \
        p1_.x = PERM2(G1_[1], G1_[0]); p1_.y = PERM2(G1_[3], G1_[2]);                    \
        char* lb_ = (char*)&Abuf[(bufi)][0];                                             \
        *(uint2*)(lb_ + wb0) = p0_;                                                      \
        *(uint2*)(lb_ + wb1) = p1_;                                                      \
    } while (0)

#define COMPUTE(bufi, BS) do {                                                           \
        const char* ab_ = (const char*)&Abuf[(bufi)][0];                                 \
        const int swz_ = (l31 & 7) << 4;                                                 \
        _Pragma("unroll")                                                                \
        for (int kf_ = 0; kf_ < 4; kf_++) {                                              \
            const int ko_ = (kf_ * 32 + half * 16) ^ swz_;                               \
            bf16x8 a0_ = *(const bf16x8*)(ab_ + l31 * 128 + ko_);                        \
            bf16x8 a1_ = *(const bf16x8*)(ab_ + (32 + l31) * 128 + ko_);                 \
            acc0 = __builtin_amdgcn_mfma_f32_32x32x16_bf16(a0_, BS[kf_], acc0, 0, 0, 0); \
            acc1 = __builtin_amdgcn_mfma_f32_32x32x16_bf16(a1_, BS[kf_], acc1, 0, 0, 0); \
        }                                                                                \
        SB0;                                                                             \
    } while (0)

// entry invariant at step s: queue = [B(s):4][G(s+1):2][G(s+2):2]
#define BODY(s_, BC, BN, GS0, GS1, WN, DOB, DOG, DOCONV) do {                            \
        if (DOB) LOADB(BN, (s_) + 1);                                                    \
        WAITV(WN);                       /* retire B(s) and G(s+1) */                    \
        if (DOCONV) CONV(GS0, GS1, ((s_) + 1) & 1);                                      \
        if (DOG) GLOAD(GS0, GS1, (s_) + 3);                                              \
        COMPUTE((s_) & 1, BC);                                                           \
        LGKM0BAR;                                                                        \
    } while (0)

    // prologue -> entry invariant for s=0: [B0:4][G1:2][G2:2], tile0 in buf0
    GLOAD(GA0, GA1, 0);
    LOADB(BX, 0);
    GLOAD(GB0, GB1, 1);
    WAITV(6);                            // G0 landed
    CONV(GA0, GA1, 0);
    GLOAD(GA0, GA1, 2);
    LGKM0BAR;

    for (int s = 0; s < 12; s += 2) {
        BODY(s,     BX, BY, GB0, GB1, 6, 1, 1, 1);
        BODY(s + 1, BY, BX, GA0, GA1, 6, 1, 1, 1);
    }
    BODY(12, BX, BY, GB0, GB1, 6, 1, 1, 1);   // loads B13, G15; converts G13
    BODY(13, BY, BX, GA0, GA1, 6, 1, 0, 1);   // loads B14; converts G14
    BODY(14, BX, BY, GB0, GB1, 4, 1, 0, 1);   // loads B15; converts G15
    WAITV(0);
    COMPUTE(1, BY);                           // s = 15

#undef BODY
#undef COMPUTE
#undef CONV
#undef PERM2
#undef LOADB
#undef GLOAD

    // exact f32 row sums: reduce each 16-thread col-group (xor 1,2,4,8 keeps row fixed)
    {
        float v0 = sm0, v1 = sm1;
#pragma unroll
        for (int o = 1; o <= 8; o <<= 1) {
            v0 += __shfl_xor(v0, o, 64);
            v1 += __shfl_xor(v1, o, 64);
        }
        if ((lane & 15) == 0) {
            rowsum_s[srow] = v0;
            rowsum_s[32 + srow] = v1;
        }
    }
    __syncthreads();

    // epilogue: tot = sum over (row,col) of [q + p*(rs - 2q)] / cp
    // C/D 32x32: col = lane&31, row = (reg&3) + 8*(reg>>2) + 4*(lane>>5)
    const float rcp = 1.0f / cp[wv * 32 + l31];
    float tot = 0.f;
#pragma unroll
    for (int reg = 0; reg < 16; reg++) {
        const int r0 = (reg & 3) + 8 * (reg >> 2) + 4 * half;
        {
            const float rs = rowsum_s[r0];
            const float p = pl[(size_t)(m0 + r0) * K_CL + wv * 32 + l31];
            const float q = acc0[reg];
            tot += (q + p * (rs - 2.0f * q)) * rcp;
        }
        {
            const float rs = rowsum_s[32 + r0];
            const float p = pl[(size_t)(m0 + 32 + r0) * K_CL + wv * 32 + l31];
            const float q = acc1[reg];
            tot += (q + p * (rs - 2.0f * q)) * rcp;
        }
    }
    for (int o = 32; o; o >>= 1) tot += __shfl_down(tot, o, 64);
    if (lane == 0) red[wv] = tot;
    __syncthreads();
    if (tid == 0) {
        float s = 0.f;
#pragma unroll
        for (int i = 0; i < 8; i++) s += red[i];
        atomicAdd(out, s);
    }

#undef WAITV
#undef LGKM0BAR
#undef SB0
}

extern "C" void kernel_launch(void* const* d_in, const int* in_sizes, int n_in,
                              void* d_out, int out_size, void* d_ws, size_t ws_size,
                              hipStream_t stream) {
    const float* w  = (const float*)d_in[0];
    const float* pl = (const float*)d_in[1];
    const float* pr = (const float*)d_in[2];
    const float* cp = (const float*)d_in[3];
    float* out = (float*)d_out;

    u16* Bpack = (u16*)d_ws;   // 4 MB

    k_prep<<<dim3(512), dim3(256), 0, stream>>>(pr, Bpack, out);
    k_main<<<dim3(128 * NSLAB), dim3(512), 0, stream>>>(w, pl, Bpack, cp, out);
}

// Round 12
// 73.284 us; speedup vs baseline: 1.9206x; 1.9206x over previous
//
#include <hip/hip_runtime.h>
#include <stdint.h>

#define A_DIM 8192
#define B_DIM 8192
#define K_CL  256
#define NSLAB 8
#define SLABW 1024              // k-columns per slab
#define NKS   32                // K-steps of 32 per slab

typedef short bf16x8 __attribute__((ext_vector_type(8)));
typedef float f32x4  __attribute__((ext_vector_type(4)));
typedef float f32x16 __attribute__((ext_vector_type(16)));
typedef unsigned short u16;

__device__ __forceinline__ u16 f2bf(float f) {
    unsigned int u = __float_as_uint(f);
    u += 0x7fffu + ((u >> 16) & 1u);   // RNE (prep only)
    return (u16)(u >> 16);
}

// ---------- prep: pack p_r into 32x32x16 MFMA B-fragment layout, bf16 ----------
// Bpack[((kb2*8 + c2)*64 + lane)*8 + j] = bf16(p_r[kb2*16 + (lane>>5)*8 + j][c2*32 + (lane&31)])
__global__ __launch_bounds__(256) void k_prep(const float* __restrict__ pr,
                                              u16* __restrict__ Bpack,
                                              float* __restrict__ out) {
    const int kb2 = blockIdx.x;          // 0..511
    const int t = threadIdx.x;
    if (kb2 == 0 && t == 0) out[0] = 0.0f;
    const int lane = t & 63, wv = t >> 6;
    const int l31 = lane & 31, half = lane >> 5;
#pragma unroll
    for (int ci = 0; ci < 2; ci++) {
        const int c2 = wv * 2 + ci;
        float v[8];
#pragma unroll
        for (int j = 0; j < 8; j++)
            v[j] = pr[(size_t)(kb2 * 16 + half * 8 + j) * K_CL + c2 * 32 + l31];
        union { bf16x8 b; unsigned int u[4]; } o;
#pragma unroll
        for (int j = 0; j < 4; j++)
            o.u[j] = (unsigned int)f2bf(v[2 * j]) | ((unsigned int)f2bf(v[2 * j + 1]) << 16);
        *(bf16x8*)(Bpack + ((size_t)(kb2 * 8 + c2) * 64 + lane) * 8) = o.b;
    }
}

// ---------- main: A direct HBM->VGPR frags; B memcpy->LDS; one vmcnt(4)+barrier/step ----------
__global__ __launch_bounds__(256, 2) void k_main(const float* __restrict__ w,
                                                 const float* __restrict__ pl,
                                                 const u16* __restrict__ Bpack,
                                                 const float* __restrict__ cp,
                                                 float* __restrict__ out) {
    __shared__ u16 Bl[2][8192];          // 2 x 16 KB ring (one K-step of B frags each)
    __shared__ float rowsum_s[4][32];
    __shared__ float red[4];

    const int bid = blockIdx.x;
    const int slab = bid & 7;            // XCD-pinned 512 KB Bpack slice
    const int m0b = (bid >> 3) * 128;
    const int tid = threadIdx.x;
    const int lane = tid & 63, wv = tid >> 6;
    const int l31 = lane & 31, half = lane >> 5;
    const int m0w = m0b + wv * 32;       // this wave's 32 rows

    // A fragment source: lane covers row l31, k-halves half*8..+7 of each 16-wide kf
    const float* wrow = w + (size_t)(m0w + l31) * B_DIM + slab * SLABW + half * 8;
    // B slab slice: step s = contiguous 16 KB at bsrc + s*16384
    const char* bsrc = (const char*)Bpack + (size_t)slab * 64 * 8192;

    f32x16 acc[8];                       // c2 = 0..7 (all 256 cols), rows = wave's 32
#pragma unroll
    for (int i = 0; i < 8; i++)
#pragma unroll
        for (int r = 0; r < 16; r++) acc[i][r] = 0.f;
    float sm = 0.f;                      // lane-local exact row-sum partial (row l31, k-half)

    f32x4 Ga[4], Gb[4];

#define SB0 __builtin_amdgcn_sched_barrier(0)
#define WAITV(n) do { asm volatile("s_waitcnt vmcnt(" #n ")" ::: "memory"); SB0; } while (0)
#define BAR do { __builtin_amdgcn_s_barrier(); SB0; } while (0)

#define STAGEB(bufi, s_) do {                                                            \
        const char* sp_ = bsrc + (size_t)(s_) * 16384 + tid * 16;                        \
        char* dp_ = (char*)&Bl[(bufi)][0] + tid * 16;                                    \
        _Pragma("unroll")                                                                \
        for (int j_ = 0; j_ < 4; j_++)                                                   \
            __builtin_amdgcn_global_load_lds(                                            \
                (const __attribute__((address_space(1))) void*)(sp_ + j_ * 4096),        \
                (__attribute__((address_space(3))) void*)(dp_ + j_ * 4096), 16, 0, 0);   \
        SB0;                                                                             \
    } while (0)

#define GLOADA(GS, s_) do {                                                              \
        GS[0] = *(const f32x4*)(wrow + (s_) * 32);                                       \
        GS[1] = *(const f32x4*)(wrow + (s_) * 32 + 4);                                   \
        GS[2] = *(const f32x4*)(wrow + (s_) * 32 + 16);                                  \
        GS[3] = *(const f32x4*)(wrow + (s_) * 32 + 20);                                  \
        SB0;                                                                             \
    } while (0)

#define PERM2(hi, lo) __builtin_amdgcn_perm(__float_as_uint(hi), __float_as_uint(lo), 0x07060302u)

#define KF(GS, i0, i1, kf_, lb_) do {                                                    \
        union { bf16x8 v; unsigned int u[4]; } a_;                                       \
        a_.u[0] = PERM2(GS[i0][1], GS[i0][0]);                                           \
        a_.u[1] = PERM2(GS[i0][3], GS[i0][2]);                                           \
        a_.u[2] = PERM2(GS[i1][1], GS[i1][0]);                                           \
        a_.u[3] = PERM2(GS[i1][3], GS[i1][2]);                                           \
        sm += GS[i0][0] + GS[i0][1] + GS[i0][2] + GS[i0][3]                              \
            + GS[i1][0] + GS[i1][1] + GS[i1][2] + GS[i1][3];                             \
        const u16* bb_ = (lb_) + (kf_) * 4096 + lane * 8;                                \
        _Pragma("unroll")                                                                \
        for (int c_ = 0; c_ < 8; c_++) {                                                 \
            bf16x8 bf_ = *(const bf16x8*)(bb_ + c_ * 512);                               \
            acc[c_] = __builtin_amdgcn_mfma_f32_32x32x16_bf16(a_.v, bf_, acc[c_], 0, 0, 0); \
        }                                                                                \
    } while (0)

// step s: entry queue = [A(s+1):4]; stage B(s+1); compute with A(s) regs + B(s) LDS;
// issue A(s+2); vmcnt(4) retires A(s+1)+B(s+1), A(s+2) crosses the barrier in flight.
#define STEP(s_, GC) do {                                                                \
        STAGEB(((s_) + 1) & 1, (s_) + 1);                                                \
        const u16* lb_ = &Bl[(s_) & 1][0];                                               \
        KF(GC, 0, 1, 0, lb_);                                                            \
        KF(GC, 2, 3, 1, lb_);                                                            \
        GLOADA(GC, (s_) + 2);                                                            \
        WAITV(4);                                                                        \
        BAR;                                                                             \
    } while (0)

    // prologue: queue [B0:4][A0:4][A1:4] -> vmcnt(4) retires B0,A0; [A1:4] remains
    STAGEB(0, 0);
    GLOADA(Ga, 0);
    GLOADA(Gb, 1);
    WAITV(4);
    BAR;

    for (int s = 0; s < 30; s += 2) {    // s = 0..29
        STEP(s, Ga);
        STEP(s + 1, Gb);
    }
    // step 30: stage B31, compute A30/B30, no A-prefetch; drain all before last barrier
    {
        STAGEB(1, 31);
        const u16* lb_ = &Bl[0][0];
        KF(Ga, 0, 1, 0, lb_);
        KF(Ga, 2, 3, 1, lb_);
        WAITV(0);
        BAR;
    }
    // step 31: compute only
    {
        const u16* lb_ = &Bl[1][0];
        KF(Gb, 0, 1, 0, lb_);
        KF(Gb, 2, 3, 1, lb_);
    }

#undef STEP
#undef KF
#undef PERM2
#undef GLOADA
#undef STAGEB

    // exact row sums: lane holds (row l31, k-half); combine halves, lanes 0-31 hold rows
    {
        float v = sm + __shfl_xor(sm, 32, 64);
        if (lane < 32) rowsum_s[wv][l31] = v;
    }

    float rcp_cp[8];
#pragma unroll
    for (int c2 = 0; c2 < 8; c2++)
        rcp_cp[c2] = 1.0f / cp[c2 * 32 + l31];

    // epilogue: tot = sum over (row,col) of [q + p*(rs - 2q)] / cp
    // C/D 32x32: col = lane&31, row = (reg&3) + 8*(reg>>2) + 4*(lane>>5)
    float tot = 0.f;
#pragma unroll
    for (int reg = 0; reg < 16; reg++) {
        const int lrow = (reg & 3) + 8 * (reg >> 2) + 4 * half;
        const float rs = rowsum_s[wv][lrow];
        const float* plrow = pl + (size_t)(m0w + lrow) * K_CL + l31;
#pragma unroll
        for (int c2 = 0; c2 < 8; c2++) {
            const float q = acc[c2][reg];
            const float p = plrow[c2 * 32];
            tot += (q + p * (rs - 2.0f * q)) * rcp_cp[c2];
        }
    }
    for (int o = 32; o; o >>= 1) tot += __shfl_down(tot, o, 64);
    if (lane == 0) red[wv] = tot;
    __syncthreads();
    if (tid == 0) atomicAdd(out, red[0] + red[1] + red[2] + red[3]);

#undef WAITV
#undef BAR
#undef SB0
}

extern "C" void kernel_launch(void* const* d_in, const int* in_sizes, int n_in,
                              void* d_out, int out_size, void* d_ws, size_t ws_size,
                              hipStream_t stream) {
    const float* w  = (const float*)d_in[0];
    const float* pl = (const float*)d_in[1];
    const float* pr = (const float*)d_in[2];
    const float* cp = (const float*)d_in[3];
    float* out = (float*)d_out;

    u16* Bpack = (u16*)d_ws;   // 4 MB

    k_prep<<<dim3(512), dim3(256), 0, stream>>>(pr, Bpack, out);
    k_main<<<dim3(64 * NSLAB), dim3(256), 0, stream>>>(w, pl, Bpack, cp, out);
}